// Round 1
// baseline (10489.211 us; speedup 1.0000x reference)
//
#include <hip/hip_runtime.h>
#include <cstdint>
#include <cstddef>

#define B_SZ 64
#define L_SEQ 196
#define D_MODEL 192
#define D_INNER 384
#define D_STATE 16
#define DT_RANK 12
#define DEPTH 24
#define N_CLS 1000
#define M_TOK (B_SZ * L_SEQ)   // 12544

__device__ __forceinline__ float sigmoidf_(float x) { return 1.f / (1.f + __expf(-x)); }

// ---------------------------------------------------------------------------
// Patch embedding: 16x16 stride-16 conv == GEMM over gathered patches.
// 8 tokens per block staged in LDS; 192 threads each own one output channel.
// ---------------------------------------------------------------------------
__global__ __launch_bounds__(192) void patch_embed_k(
    const float* __restrict__ x, const float* __restrict__ pw,
    const float* __restrict__ pb, float* __restrict__ hidden)
{
    __shared__ float tile[8 * 768];
    const int tid  = threadIdx.x;
    const int tok0 = blockIdx.x * 8;

    for (int idx = tid; idx < 8 * 768; idx += 192) {
        int t   = idx / 768;
        int k   = idx - t * 768;
        int ci  = k >> 8;          // /256
        int rem = k & 255;
        int rr  = rem >> 4;
        int cc  = rem & 15;
        int tok = tok0 + t;
        int b   = tok / L_SEQ;
        int l   = tok - b * L_SEQ;
        int py  = l / 14;
        int px  = l - py * 14;
        tile[idx] = x[(((size_t)b * 3 + ci) * 224 + (py * 16 + rr)) * 224 + (px * 16 + cc)];
    }
    __syncthreads();

    const int co = tid;
    float acc[8];
    const float bias = pb[co];
#pragma unroll
    for (int t = 0; t < 8; ++t) acc[t] = bias;

    const float* wrow = pw + (size_t)co * 768;
    for (int k = 0; k < 768; ++k) {
        float w = wrow[k];
#pragma unroll
        for (int t = 0; t < 8; ++t) acc[t] += w * tile[t * 768 + k];
    }
#pragma unroll
    for (int t = 0; t < 8; ++t)
        hidden[(size_t)(tok0 + t) * D_MODEL + co] = acc[t];
}

// ---------------------------------------------------------------------------
// residual = (first ? hidden : residual + hidden); hn = LayerNorm(residual)*w+b
// one 64-thread wave per token, 3 elements/thread, shuffle reduction.
// ---------------------------------------------------------------------------
__global__ __launch_bounds__(64) void resid_ln_k(
    const float* __restrict__ hidden, float* __restrict__ residual,
    float* __restrict__ hn, const float* __restrict__ w,
    const float* __restrict__ b, int first)
{
    const int tok = blockIdx.x;
    const int tid = threadIdx.x;
    const float* hrow = hidden + (size_t)tok * D_MODEL;
    float* rrow = residual + (size_t)tok * D_MODEL;

    float v[3];
    float s = 0.f, s2 = 0.f;
#pragma unroll
    for (int i = 0; i < 3; ++i) {
        int d = tid + 64 * i;
        float h = hrow[d];
        float r = first ? h : (rrow[d] + h);
        rrow[d] = r;
        v[i] = r; s += r; s2 += r * r;
    }
#pragma unroll
    for (int off = 32; off > 0; off >>= 1) {
        s  += __shfl_down(s, off);
        s2 += __shfl_down(s2, off);
    }
    s  = __shfl(s, 0);
    s2 = __shfl(s2, 0);
    float mu   = s * (1.f / 192.f);
    float var  = s2 * (1.f / 192.f) - mu * mu;
    float rstd = rsqrtf(var + 1e-5f);

    float* orow = hn + (size_t)tok * D_MODEL;
#pragma unroll
    for (int i = 0; i < 3; ++i) {
        int d = tid + 64 * i;
        orow[d] = (v[i] - mu) * rstd * w[d] + b[d];
    }
}

// ---------------------------------------------------------------------------
// C[M,N] = A[M,K] * W[N,K]^T   (fp32, 64x64 tile, BK=16, 4x4 per thread)
// M is always a multiple of 64, K a multiple of 16; N may be ragged (44).
// ---------------------------------------------------------------------------
__global__ __launch_bounds__(256) void gemm_k(
    const float* __restrict__ A, const float* __restrict__ W,
    float* __restrict__ C, int M, int N, int K)
{
    __shared__ __align__(16) float As[16][68];
    __shared__ __align__(16) float Bs[16][68];
    const int tid = threadIdx.x;
    const int tx = tid & 15, ty = tid >> 4;
    const int m0 = blockIdx.x * 64, n0 = blockIdx.y * 64;
    const int lj = tid & 15, li = tid >> 4;

    float acc[4][4] = {};

    for (int k0 = 0; k0 < K; k0 += 16) {
#pragma unroll
        for (int p = 0; p < 4; ++p) {
            int m = m0 + li + 16 * p;
            As[lj][li + 16 * p] = A[(size_t)m * K + k0 + lj];
        }
#pragma unroll
        for (int p = 0; p < 4; ++p) {
            int n = n0 + li + 16 * p;
            Bs[lj][li + 16 * p] = (n < N) ? W[(size_t)n * K + k0 + lj] : 0.f;
        }
        __syncthreads();
#pragma unroll
        for (int kk = 0; kk < 16; ++kk) {
            float a[4], bb[4];
#pragma unroll
            for (int i = 0; i < 4; ++i) a[i]  = As[kk][ty * 4 + i];
#pragma unroll
            for (int j = 0; j < 4; ++j) bb[j] = Bs[kk][tx * 4 + j];
#pragma unroll
            for (int i = 0; i < 4; ++i)
#pragma unroll
                for (int j = 0; j < 4; ++j)
                    acc[i][j] += a[i] * bb[j];
        }
        __syncthreads();
    }
#pragma unroll
    for (int i = 0; i < 4; ++i) {
        int m = m0 + ty * 4 + i;
#pragma unroll
        for (int j = 0; j < 4; ++j) {
            int n = n0 + tx * 4 + j;
            if (n < N) C[(size_t)m * N + n] = acc[i][j];
        }
    }
}

// ---------------------------------------------------------------------------
// Depthwise causal conv1d (k=4, left pad 3) + SiLU over the x-half of xz.
// One thread per (b,d) channel, sliding window in registers.
// xz layout (B,L,768); output xb layout (B,L,384).
// ---------------------------------------------------------------------------
__global__ __launch_bounds__(64) void conv_silu_k(
    const float* __restrict__ xz, const float* __restrict__ cw,
    const float* __restrict__ cb, float* __restrict__ xb)
{
    const int b = blockIdx.x;
    const int d = blockIdx.y * 64 + threadIdx.x;
    const float w0 = cw[d * 4 + 0], w1 = cw[d * 4 + 1],
                w2 = cw[d * 4 + 2], w3 = cw[d * 4 + 3];
    const float bias = cb[d];
    const float* src = xz + (size_t)b * L_SEQ * 768 + d;
    float*       dst = xb + (size_t)b * L_SEQ * D_INNER + d;

    float x0 = 0.f, x1 = 0.f, x2 = 0.f;
    for (int l = 0; l < L_SEQ; ++l) {
        float x3 = src[l * 768];
        float a  = w0 * x0 + w1 * x1 + w2 * x2 + w3 * x3 + bias;
        dst[l * D_INNER] = a * sigmoidf_(a);
        x0 = x1; x1 = x2; x2 = x3;
    }
}

// ---------------------------------------------------------------------------
// Selective scan, fused with dt_proj+softplus, D-skip and silu(z) gating.
// One thread per (b,d): 16-state recurrence in registers over L=196 steps.
// y may alias u (each element read then overwritten by the same thread).
// ---------------------------------------------------------------------------
__global__ __launch_bounds__(64) void scan_gate_k(
    const float* u, const float* __restrict__ xdbl, const float* __restrict__ xz,
    const float* __restrict__ dtw, const float* __restrict__ dtb,
    const float* __restrict__ A_log, const float* __restrict__ Dskip,
    float* y)
{
    const int b = blockIdx.x;
    const int d = blockIdx.y * 64 + threadIdx.x;

    float A[D_STATE], h[D_STATE];
#pragma unroll
    for (int n = 0; n < D_STATE; ++n) {
        A[n] = -__expf(A_log[d * D_STATE + n]);
        h[n] = 0.f;
    }
    float wdt[DT_RANK];
#pragma unroll
    for (int r = 0; r < DT_RANK; ++r) wdt[r] = dtw[d * DT_RANK + r];
    const float bdt = dtb[d];
    const float Dv  = Dskip[d];

    const float* xd = xdbl + (size_t)b * L_SEQ * 44;
    const float* ub = u    + (size_t)b * L_SEQ * D_INNER + d;
    const float* zb = xz   + (size_t)b * L_SEQ * 768 + D_INNER + d;
    float*       yb = y    + (size_t)b * L_SEQ * D_INNER + d;

    for (int l = 0; l < L_SEQ; ++l) {
        const float* row = xd + l * 44;          // uniform address across wave
        float dtraw = bdt;
#pragma unroll
        for (int r = 0; r < DT_RANK; ++r) dtraw += row[r] * wdt[r];
        float dt = (dtraw > 20.f) ? dtraw : log1pf(__expf(dtraw));
        float uv = ub[l * D_INNER];
        float du = dt * uv;
        float yv = 0.f;
#pragma unroll
        for (int n = 0; n < D_STATE; ++n) {
            h[n] = __expf(dt * A[n]) * h[n] + du * row[12 + n];
            yv  += h[n] * row[28 + n];
        }
        yv += uv * Dv;
        float zv = zb[l * 768];
        yb[l * D_INNER] = yv * (zv * sigmoidf_(zv));
    }
}

// ---------------------------------------------------------------------------
// Final: residual+hidden at last token only, LayerNorm -> pooled (64x192)
// ---------------------------------------------------------------------------
__global__ __launch_bounds__(64) void final_pool_k(
    const float* __restrict__ residual, const float* __restrict__ hidden,
    const float* __restrict__ w, const float* __restrict__ b,
    float* __restrict__ pooled)
{
    const int bi  = blockIdx.x;
    const int tid = threadIdx.x;
    const size_t off = ((size_t)bi * L_SEQ + (L_SEQ - 1)) * D_MODEL;

    float v[3];
    float s = 0.f, s2 = 0.f;
#pragma unroll
    for (int i = 0; i < 3; ++i) {
        int d = tid + 64 * i;
        float r = residual[off + d] + hidden[off + d];
        v[i] = r; s += r; s2 += r * r;
    }
#pragma unroll
    for (int offd = 32; offd > 0; offd >>= 1) {
        s  += __shfl_down(s, offd);
        s2 += __shfl_down(s2, offd);
    }
    s  = __shfl(s, 0);
    s2 = __shfl(s2, 0);
    float mu   = s * (1.f / 192.f);
    float var  = s2 * (1.f / 192.f) - mu * mu;
    float rstd = rsqrtf(var + 1e-5f);
#pragma unroll
    for (int i = 0; i < 3; ++i) {
        int d = tid + 64 * i;
        pooled[bi * D_MODEL + d] = (v[i] - mu) * rstd * w[d] + b[d];
    }
}

// ---------------------------------------------------------------------------
// Head: out[b,c] = pooled[b,:] . head_w[c,:] + head_b[c]
// ---------------------------------------------------------------------------
__global__ __launch_bounds__(256) void head_k(
    const float* __restrict__ pooled, const float* __restrict__ hw,
    const float* __restrict__ hb, float* __restrict__ out)
{
    __shared__ float p[D_MODEL];
    const int bi  = blockIdx.x;
    const int tid = threadIdx.x;
    if (tid < D_MODEL) p[tid] = pooled[bi * D_MODEL + tid];
    __syncthreads();
    int c = blockIdx.y * 256 + tid;
    if (c < N_CLS) {
        float acc = hb[c];
        const float* wrow = hw + (size_t)c * D_MODEL;
#pragma unroll 4
        for (int d = 0; d < D_MODEL; ++d) acc += p[d] * wrow[d];
        out[(size_t)bi * N_CLS + c] = acc;
    }
}

// ---------------------------------------------------------------------------
extern "C" void kernel_launch(void* const* d_in, const int* in_sizes, int n_in,
                              void* d_out, int out_size, void* d_ws, size_t ws_size,
                              hipStream_t stream)
{
    const float* x          = (const float*)d_in[0];
    const float* patch_w    = (const float*)d_in[1];
    const float* patch_b    = (const float*)d_in[2];
    const float* in_proj_w  = (const float*)d_in[3];
    const float* conv_w     = (const float*)d_in[4];
    const float* conv_b     = (const float*)d_in[5];
    const float* x_proj_w   = (const float*)d_in[6];
    const float* dt_proj_w  = (const float*)d_in[7];
    const float* dt_proj_b  = (const float*)d_in[8];
    const float* A_log      = (const float*)d_in[9];
    const float* D_skip     = (const float*)d_in[10];
    const float* out_proj_w = (const float*)d_in[11];
    const float* norm_w     = (const float*)d_in[12];
    const float* norm_b     = (const float*)d_in[13];
    const float* normf_w    = (const float*)d_in[14];
    const float* normf_b    = (const float*)d_in[15];
    const float* head_w     = (const float*)d_in[16];
    const float* head_b     = (const float*)d_in[17];
    float* out = (float*)d_out;

    // workspace layout (floats); total 22,240,256 floats = 88.96 MB
    float* ws       = (float*)d_ws;
    float* residual = ws;                 // 2,408,448
    float* hidden   = ws + 2408448;       // 2,408,448
    float* hn       = ws + 4816896;       // 2,408,448
    float* xz       = ws + 7225344;       // 9,633,792  (B,L,768)
    float* xb       = ws + 16859136;      // 4,816,896  (B,L,384) u then y
    float* xdbl     = ws + 21676032;      //   551,936  (B,L,44)
    float* pooled   = ws + 22227968;      //    12,288

    patch_embed_k<<<M_TOK / 8, 192, 0, stream>>>(x, patch_w, patch_b, hidden);

    for (int i = 0; i < DEPTH; ++i) {
        resid_ln_k<<<M_TOK, 64, 0, stream>>>(
            hidden, residual, hn, norm_w + i * D_MODEL, norm_b + i * D_MODEL,
            (i == 0) ? 1 : 0);
        gemm_k<<<dim3(M_TOK / 64, 768 / 64), 256, 0, stream>>>(
            hn, in_proj_w + (size_t)i * 768 * D_MODEL, xz, M_TOK, 768, D_MODEL);
        conv_silu_k<<<dim3(B_SZ, 6), 64, 0, stream>>>(
            xz, conv_w + (size_t)i * D_INNER * 4, conv_b + i * D_INNER, xb);
        gemm_k<<<dim3(M_TOK / 64, 1), 256, 0, stream>>>(
            xb, x_proj_w + (size_t)i * 44 * D_INNER, xdbl, M_TOK, 44, D_INNER);
        scan_gate_k<<<dim3(B_SZ, 6), 64, 0, stream>>>(
            xb, xdbl, xz,
            dt_proj_w + (size_t)i * D_INNER * DT_RANK, dt_proj_b + i * D_INNER,
            A_log + (size_t)i * D_INNER * D_STATE, D_skip + i * D_INNER, xb);
        gemm_k<<<dim3(M_TOK / 64, 192 / 64), 256, 0, stream>>>(
            xb, out_proj_w + (size_t)i * D_MODEL * D_INNER, hidden, M_TOK, D_MODEL, D_INNER);
    }

    final_pool_k<<<B_SZ, 64, 0, stream>>>(residual, hidden, normf_w, normf_b, pooled);
    head_k<<<dim3(B_SZ, 4), 256, 0, stream>>>(pooled, head_w, head_b, out);
}

// Round 2
// 8249.813 us; speedup vs baseline: 1.2714x; 1.2714x over previous
//
#include <hip/hip_runtime.h>
#include <cstdint>
#include <cstddef>

#define B_SZ 64
#define L_SEQ 196
#define D_MODEL 192
#define D_INNER 384
#define D_STATE 16
#define DT_RANK 12
#define DEPTH 24
#define N_CLS 1000
#define M_TOK (B_SZ * L_SEQ)   // 12544
#define N_CHUNK 14
#define CH_LEN 14

__device__ __forceinline__ float sigmoidf_(float x) { return 1.f / (1.f + __expf(-x)); }

// ---------------------------------------------------------------------------
// Patch embedding: 16x16 stride-16 conv == GEMM over gathered patches.
// ---------------------------------------------------------------------------
__global__ __launch_bounds__(192) void patch_embed_k(
    const float* __restrict__ x, const float* __restrict__ pw,
    const float* __restrict__ pb, float* __restrict__ hidden)
{
    __shared__ float tile[8 * 768];
    const int tid  = threadIdx.x;
    const int tok0 = blockIdx.x * 8;

    for (int idx = tid; idx < 8 * 768; idx += 192) {
        int t   = idx / 768;
        int k   = idx - t * 768;
        int ci  = k >> 8;
        int rem = k & 255;
        int rr  = rem >> 4;
        int cc  = rem & 15;
        int tok = tok0 + t;
        int b   = tok / L_SEQ;
        int l   = tok - b * L_SEQ;
        int py  = l / 14;
        int px  = l - py * 14;
        tile[idx] = x[(((size_t)b * 3 + ci) * 224 + (py * 16 + rr)) * 224 + (px * 16 + cc)];
    }
    __syncthreads();

    const int co = tid;
    float acc[8];
    const float bias = pb[co];
#pragma unroll
    for (int t = 0; t < 8; ++t) acc[t] = bias;

    const float* wrow = pw + (size_t)co * 768;
    for (int k = 0; k < 768; ++k) {
        float w = wrow[k];
#pragma unroll
        for (int t = 0; t < 8; ++t) acc[t] += w * tile[t * 768 + k];
    }
#pragma unroll
    for (int t = 0; t < 8; ++t)
        hidden[(size_t)(tok0 + t) * D_MODEL + co] = acc[t];
}

// ---------------------------------------------------------------------------
// residual = (first ? hidden : residual + hidden); hn = LayerNorm(residual)
// ---------------------------------------------------------------------------
__global__ __launch_bounds__(64) void resid_ln_k(
    const float* __restrict__ hidden, float* __restrict__ residual,
    float* __restrict__ hn, const float* __restrict__ w,
    const float* __restrict__ b, int first)
{
    const int tok = blockIdx.x;
    const int tid = threadIdx.x;
    const float* hrow = hidden + (size_t)tok * D_MODEL;
    float* rrow = residual + (size_t)tok * D_MODEL;

    float v[3];
    float s = 0.f, s2 = 0.f;
#pragma unroll
    for (int i = 0; i < 3; ++i) {
        int d = tid + 64 * i;
        float h = hrow[d];
        float r = first ? h : (rrow[d] + h);
        rrow[d] = r;
        v[i] = r; s += r; s2 += r * r;
    }
#pragma unroll
    for (int off = 32; off > 0; off >>= 1) {
        s  += __shfl_down(s, off);
        s2 += __shfl_down(s2, off);
    }
    s  = __shfl(s, 0);
    s2 = __shfl(s2, 0);
    float mu   = s * (1.f / 192.f);
    float var  = s2 * (1.f / 192.f) - mu * mu;
    float rstd = rsqrtf(var + 1e-5f);

    float* orow = hn + (size_t)tok * D_MODEL;
#pragma unroll
    for (int i = 0; i < 3; ++i) {
        int d = tid + 64 * i;
        orow[d] = (v[i] - mu) * rstd * w[d] + b[d];
    }
}

// ---------------------------------------------------------------------------
// C[M,N] = A[M,K] * W[N,K]^T   (fp32, 64x64 tile, BK=16, 4x4 per thread)
// ---------------------------------------------------------------------------
__global__ __launch_bounds__(256) void gemm_k(
    const float* __restrict__ A, const float* __restrict__ W,
    float* __restrict__ C, int M, int N, int K)
{
    __shared__ __align__(16) float As[16][68];
    __shared__ __align__(16) float Bs[16][68];
    const int tid = threadIdx.x;
    const int tx = tid & 15, ty = tid >> 4;
    const int m0 = blockIdx.x * 64, n0 = blockIdx.y * 64;
    const int lj = tid & 15, li = tid >> 4;

    float acc[4][4] = {};

    for (int k0 = 0; k0 < K; k0 += 16) {
#pragma unroll
        for (int p = 0; p < 4; ++p) {
            int m = m0 + li + 16 * p;
            As[lj][li + 16 * p] = A[(size_t)m * K + k0 + lj];
        }
#pragma unroll
        for (int p = 0; p < 4; ++p) {
            int n = n0 + li + 16 * p;
            Bs[lj][li + 16 * p] = (n < N) ? W[(size_t)n * K + k0 + lj] : 0.f;
        }
        __syncthreads();
#pragma unroll
        for (int kk = 0; kk < 16; ++kk) {
            float a[4], bb[4];
#pragma unroll
            for (int i = 0; i < 4; ++i) a[i]  = As[kk][ty * 4 + i];
#pragma unroll
            for (int j = 0; j < 4; ++j) bb[j] = Bs[kk][tx * 4 + j];
#pragma unroll
            for (int i = 0; i < 4; ++i)
#pragma unroll
                for (int j = 0; j < 4; ++j)
                    acc[i][j] += a[i] * bb[j];
        }
        __syncthreads();
    }
#pragma unroll
    for (int i = 0; i < 4; ++i) {
        int m = m0 + ty * 4 + i;
#pragma unroll
        for (int j = 0; j < 4; ++j) {
            int n = n0 + tx * 4 + j;
            if (n < N) C[(size_t)m * N + n] = acc[i][j];
        }
    }
}

// ---------------------------------------------------------------------------
// Depthwise causal conv1d (k=4, left pad 3) + SiLU over the x-half of xz.
// ---------------------------------------------------------------------------
__global__ __launch_bounds__(64) void conv_silu_k(
    const float* __restrict__ xz, const float* __restrict__ cw,
    const float* __restrict__ cb, float* __restrict__ xb)
{
    const int b = blockIdx.x;
    const int d = blockIdx.y * 64 + threadIdx.x;
    const float w0 = cw[d * 4 + 0], w1 = cw[d * 4 + 1],
                w2 = cw[d * 4 + 2], w3 = cw[d * 4 + 3];
    const float bias = cb[d];
    const float* src = xz + (size_t)b * L_SEQ * 768 + d;
    float*       dst = xb + (size_t)b * L_SEQ * D_INNER + d;

    float x0 = 0.f, x1 = 0.f, x2 = 0.f;
    for (int l = 0; l < L_SEQ; ++l) {
        float x3 = src[l * 768];
        float a  = w0 * x0 + w1 * x1 + w2 * x2 + w3 * x3 + bias;
        dst[l * D_INNER] = a * sigmoidf_(a);
        x0 = x1; x1 = x2; x2 = x3;
    }
}

// ---------------------------------------------------------------------------
// Chunked parallel selective scan (fused dt_proj+softplus, D-skip, silu(z)).
//
// Block = 1024 threads = 16 waves, per (batch, 64-channel group).
//   lane = threadIdx.x & 63  -> channel within group
//   wave = threadIdx.x >> 6  -> chunk index (waves 0..13 active in A/C)
// Pass A: each wave runs its 14-step chunk from h=0, records h_local[16]
//         and dt_sum (exp-product identity: prod exp(dt*A) = exp(A*sum dt)).
//         dt and u values for the chunk stay in registers for pass C.
// Pass B: all 1024 threads = (d, n) pairs serially combine the 14 chunk
//         summaries in LDS, overwriting h_local[c] with h_init[c] in place.
// Pass C: each wave replays its chunk from h_init and writes gated y.
// y may alias u: pass C reads u only from registers (pass A copies).
// ---------------------------------------------------------------------------
__global__ __launch_bounds__(1024) void scan_chunked_k(
    const float* __restrict__ u, const float* __restrict__ xdbl,
    const float* __restrict__ xz,
    const float* __restrict__ dtw, const float* __restrict__ dtb,
    const float* __restrict__ A_log, const float* __restrict__ Dskip,
    float* __restrict__ y)
{
    __shared__ float hl[N_CHUNK * 64 * 17];   // [chunk][d][state], pad 17
    __shared__ float dts[N_CHUNK * 64];       // [chunk][d]

    const int b    = blockIdx.x;
    const int dg   = blockIdx.y;
    const int t    = threadIdx.x;
    const int lane = t & 63;
    const int wv   = t >> 6;
    const int d    = dg * 64 + lane;

    const float* xd = xdbl + (size_t)b * L_SEQ * 44;

    float A[D_STATE], wdt[DT_RANK];
    float dt[CH_LEN], uv[CH_LEN];
    float bdt = 0.f, Dv = 0.f;

    if (wv < N_CHUNK) {
#pragma unroll
        for (int n = 0; n < D_STATE; ++n) A[n] = -__expf(A_log[d * D_STATE + n]);
#pragma unroll
        for (int r = 0; r < DT_RANK; ++r) wdt[r] = dtw[d * DT_RANK + r];
        bdt = dtb[d];
        Dv  = Dskip[d];

        // ---- Pass A: chunk-local scan from h = 0 ----
        const int l0 = wv * CH_LEN;
        float h[D_STATE];
#pragma unroll
        for (int n = 0; n < D_STATE; ++n) h[n] = 0.f;
        float dtsum = 0.f;
#pragma unroll
        for (int s = 0; s < CH_LEN; ++s) {
            const int l = l0 + s;
            const float* row = xd + l * 44;
            float dtraw = bdt;
#pragma unroll
            for (int r = 0; r < DT_RANK; ++r) dtraw += row[r] * wdt[r];
            float dtv = (dtraw > 20.f) ? dtraw : log1pf(__expf(dtraw));
            dt[s] = dtv;
            dtsum += dtv;
            float uvv = u[((size_t)b * L_SEQ + l) * D_INNER + d];
            uv[s] = uvv;
            float du = dtv * uvv;
#pragma unroll
            for (int n = 0; n < D_STATE; ++n)
                h[n] = __expf(dtv * A[n]) * h[n] + du * row[12 + n];
        }
#pragma unroll
        for (int n = 0; n < D_STATE; ++n)
            hl[(wv * 64 + lane) * 17 + n] = h[n];
        dts[wv * 64 + lane] = dtsum;
    }
    __syncthreads();

    // ---- Pass B: cross-chunk combine; hl[c] := h_init for chunk c ----
    {
        const int dB = lane;
        const int nB = wv;            // 16 waves <-> 16 states
        const float Ab = -__expf(A_log[(dg * 64 + dB) * D_STATE + nB]);
        float s = 0.f;
#pragma unroll
        for (int c = 0; c < N_CHUNK; ++c) {
            const int idx = (c * 64 + dB) * 17 + nB;
            float old = hl[idx];
            hl[idx] = s;
            s = __expf(Ab * dts[c * 64 + dB]) * s + old;
        }
    }
    __syncthreads();

    if (wv < N_CHUNK) {
        // ---- Pass C: replay chunk from h_init, emit gated y ----
        const int l0 = wv * CH_LEN;
        float h[D_STATE];
#pragma unroll
        for (int n = 0; n < D_STATE; ++n)
            h[n] = hl[(wv * 64 + lane) * 17 + n];
#pragma unroll
        for (int s = 0; s < CH_LEN; ++s) {
            const int l = l0 + s;
            const float* row = xd + l * 44;
            const float dtv = dt[s];
            const float du  = dtv * uv[s];
            float yv = 0.f;
#pragma unroll
            for (int n = 0; n < D_STATE; ++n) {
                h[n] = __expf(dtv * A[n]) * h[n] + du * row[12 + n];
                yv  += h[n] * row[28 + n];
            }
            yv += uv[s] * Dv;
            float zv = xz[((size_t)b * L_SEQ + l) * 768 + D_INNER + d];
            y[((size_t)b * L_SEQ + l) * D_INNER + d] = yv * (zv * sigmoidf_(zv));
        }
    }
}

// ---------------------------------------------------------------------------
// Final: residual+hidden at last token only, LayerNorm -> pooled (64x192)
// ---------------------------------------------------------------------------
__global__ __launch_bounds__(64) void final_pool_k(
    const float* __restrict__ residual, const float* __restrict__ hidden,
    const float* __restrict__ w, const float* __restrict__ b,
    float* __restrict__ pooled)
{
    const int bi  = blockIdx.x;
    const int tid = threadIdx.x;
    const size_t off = ((size_t)bi * L_SEQ + (L_SEQ - 1)) * D_MODEL;

    float v[3];
    float s = 0.f, s2 = 0.f;
#pragma unroll
    for (int i = 0; i < 3; ++i) {
        int d = tid + 64 * i;
        float r = residual[off + d] + hidden[off + d];
        v[i] = r; s += r; s2 += r * r;
    }
#pragma unroll
    for (int offd = 32; offd > 0; offd >>= 1) {
        s  += __shfl_down(s, offd);
        s2 += __shfl_down(s2, offd);
    }
    s  = __shfl(s, 0);
    s2 = __shfl(s2, 0);
    float mu   = s * (1.f / 192.f);
    float var  = s2 * (1.f / 192.f) - mu * mu;
    float rstd = rsqrtf(var + 1e-5f);
#pragma unroll
    for (int i = 0; i < 3; ++i) {
        int d = tid + 64 * i;
        pooled[bi * D_MODEL + d] = (v[i] - mu) * rstd * w[d] + b[d];
    }
}

// ---------------------------------------------------------------------------
// Head: out[b,c] = pooled[b,:] . head_w[c,:] + head_b[c]
// ---------------------------------------------------------------------------
__global__ __launch_bounds__(256) void head_k(
    const float* __restrict__ pooled, const float* __restrict__ hw,
    const float* __restrict__ hb, float* __restrict__ out)
{
    __shared__ float p[D_MODEL];
    const int bi  = blockIdx.x;
    const int tid = threadIdx.x;
    if (tid < D_MODEL) p[tid] = pooled[bi * D_MODEL + tid];
    __syncthreads();
    int c = blockIdx.y * 256 + tid;
    if (c < N_CLS) {
        float acc = hb[c];
        const float* wrow = hw + (size_t)c * D_MODEL;
#pragma unroll 4
        for (int d = 0; d < D_MODEL; ++d) acc += p[d] * wrow[d];
        out[(size_t)bi * N_CLS + c] = acc;
    }
}

// ---------------------------------------------------------------------------
extern "C" void kernel_launch(void* const* d_in, const int* in_sizes, int n_in,
                              void* d_out, int out_size, void* d_ws, size_t ws_size,
                              hipStream_t stream)
{
    const float* x          = (const float*)d_in[0];
    const float* patch_w    = (const float*)d_in[1];
    const float* patch_b    = (const float*)d_in[2];
    const float* in_proj_w  = (const float*)d_in[3];
    const float* conv_w     = (const float*)d_in[4];
    const float* conv_b     = (const float*)d_in[5];
    const float* x_proj_w   = (const float*)d_in[6];
    const float* dt_proj_w  = (const float*)d_in[7];
    const float* dt_proj_b  = (const float*)d_in[8];
    const float* A_log      = (const float*)d_in[9];
    const float* D_skip     = (const float*)d_in[10];
    const float* out_proj_w = (const float*)d_in[11];
    const float* norm_w     = (const float*)d_in[12];
    const float* norm_b     = (const float*)d_in[13];
    const float* normf_w    = (const float*)d_in[14];
    const float* normf_b    = (const float*)d_in[15];
    const float* head_w     = (const float*)d_in[16];
    const float* head_b     = (const float*)d_in[17];
    float* out = (float*)d_out;

    // workspace layout (floats); total 22,240,256 floats = 88.96 MB
    float* ws       = (float*)d_ws;
    float* residual = ws;                 // 2,408,448
    float* hidden   = ws + 2408448;       // 2,408,448
    float* hn       = ws + 4816896;       // 2,408,448
    float* xz       = ws + 7225344;       // 9,633,792  (B,L,768)
    float* xb       = ws + 16859136;      // 4,816,896  (B,L,384) u then y
    float* xdbl     = ws + 21676032;      //   551,936  (B,L,44)
    float* pooled   = ws + 22227968;      //    12,288

    patch_embed_k<<<M_TOK / 8, 192, 0, stream>>>(x, patch_w, patch_b, hidden);

    for (int i = 0; i < DEPTH; ++i) {
        resid_ln_k<<<M_TOK, 64, 0, stream>>>(
            hidden, residual, hn, norm_w + i * D_MODEL, norm_b + i * D_MODEL,
            (i == 0) ? 1 : 0);
        gemm_k<<<dim3(M_TOK / 64, 768 / 64), 256, 0, stream>>>(
            hn, in_proj_w + (size_t)i * 768 * D_MODEL, xz, M_TOK, 768, D_MODEL);
        conv_silu_k<<<dim3(B_SZ, 6), 64, 0, stream>>>(
            xz, conv_w + (size_t)i * D_INNER * 4, conv_b + i * D_INNER, xb);
        gemm_k<<<dim3(M_TOK / 64, 1), 256, 0, stream>>>(
            xb, x_proj_w + (size_t)i * 44 * D_INNER, xdbl, M_TOK, 44, D_INNER);
        scan_chunked_k<<<dim3(B_SZ, 6), 1024, 0, stream>>>(
            xb, xdbl, xz,
            dt_proj_w + (size_t)i * D_INNER * DT_RANK, dt_proj_b + i * D_INNER,
            A_log + (size_t)i * D_INNER * D_STATE, D_skip + i * D_INNER, xb);
        gemm_k<<<dim3(M_TOK / 64, 192 / 64), 256, 0, stream>>>(
            xb, out_proj_w + (size_t)i * D_MODEL * D_INNER, hidden, M_TOK, D_MODEL, D_INNER);
    }

    final_pool_k<<<B_SZ, 64, 0, stream>>>(residual, hidden, normf_w, normf_b, pooled);
    head_k<<<dim3(B_SZ, 4), 256, 0, stream>>>(pooled, head_w, head_b, out);
}

// Round 3
// 5362.141 us; speedup vs baseline: 1.9562x; 1.5385x over previous
//
#include <hip/hip_runtime.h>
#include <hip/hip_bf16.h>
#include <cstdint>
#include <cstddef>

#define B_SZ 64
#define L_SEQ 196
#define D_MODEL 192
#define D_INNER 384
#define D_STATE 16
#define DT_RANK 12
#define DEPTH 24
#define N_CLS 1000
#define M_TOK (B_SZ * L_SEQ)   // 12544
#define N_CHUNK 14
#define CH_LEN 14

using bf16x8 = __attribute__((ext_vector_type(8))) short;
using f32x4  = __attribute__((ext_vector_type(4))) float;
typedef __hip_bfloat16 bf16;

__device__ __forceinline__ float sigmoidf_(float x) { return 1.f / (1.f + __expf(-x)); }

// ---------------------------------------------------------------------------
// fp32 -> bf16 weight conversion (runs every launch; graph-safe)
// ---------------------------------------------------------------------------
__global__ __launch_bounds__(256) void f2bf_k(
    const float4* __restrict__ src, ushort4* __restrict__ dst, int n4)
{
    int i = blockIdx.x * 256 + threadIdx.x;
    if (i < n4) {
        float4 v = src[i];
        ushort4 o;
        bf16 h;
        h = __float2bfloat16(v.x); o.x = *(unsigned short*)&h;
        h = __float2bfloat16(v.y); o.y = *(unsigned short*)&h;
        h = __float2bfloat16(v.z); o.z = *(unsigned short*)&h;
        h = __float2bfloat16(v.w); o.w = *(unsigned short*)&h;
        dst[i] = o;
    }
}

// ---------------------------------------------------------------------------
// Patch embedding (fp32): 16x16 stride-16 conv == GEMM over gathered patches.
// ---------------------------------------------------------------------------
__global__ __launch_bounds__(192) void patch_embed_k(
    const float* __restrict__ x, const float* __restrict__ pw,
    const float* __restrict__ pb, float* __restrict__ hidden)
{
    __shared__ float tile[8 * 768];
    const int tid  = threadIdx.x;
    const int tok0 = blockIdx.x * 8;

    for (int idx = tid; idx < 8 * 768; idx += 192) {
        int t   = idx / 768;
        int k   = idx - t * 768;
        int ci  = k >> 8;
        int rem = k & 255;
        int rr  = rem >> 4;
        int cc  = rem & 15;
        int tok = tok0 + t;
        int b   = tok / L_SEQ;
        int l   = tok - b * L_SEQ;
        int py  = l / 14;
        int px  = l - py * 14;
        tile[idx] = x[(((size_t)b * 3 + ci) * 224 + (py * 16 + rr)) * 224 + (px * 16 + cc)];
    }
    __syncthreads();

    const int co = tid;
    float acc[8];
    const float bias = pb[co];
#pragma unroll
    for (int t = 0; t < 8; ++t) acc[t] = bias;

    const float* wrow = pw + (size_t)co * 768;
    for (int k = 0; k < 768; ++k) {
        float w = wrow[k];
#pragma unroll
        for (int t = 0; t < 8; ++t) acc[t] += w * tile[t * 768 + k];
    }
#pragma unroll
    for (int t = 0; t < 8; ++t)
        hidden[(size_t)(tok0 + t) * D_MODEL + co] = acc[t];
}

// ---------------------------------------------------------------------------
// residual = (first ? hidden : residual + hidden); hn = LN(residual) -> bf16
// ---------------------------------------------------------------------------
__global__ __launch_bounds__(64) void resid_ln_k(
    const float* __restrict__ hidden, float* __restrict__ residual,
    bf16* __restrict__ hn, const float* __restrict__ w,
    const float* __restrict__ b, int first)
{
    const int tok = blockIdx.x;
    const int tid = threadIdx.x;
    const float* hrow = hidden + (size_t)tok * D_MODEL;
    float* rrow = residual + (size_t)tok * D_MODEL;

    float v[3];
    float s = 0.f, s2 = 0.f;
#pragma unroll
    for (int i = 0; i < 3; ++i) {
        int d = tid + 64 * i;
        float h = hrow[d];
        float r = first ? h : (rrow[d] + h);
        rrow[d] = r;
        v[i] = r; s += r; s2 += r * r;
    }
#pragma unroll
    for (int off = 32; off > 0; off >>= 1) {
        s  += __shfl_down(s, off);
        s2 += __shfl_down(s2, off);
    }
    s  = __shfl(s, 0);
    s2 = __shfl(s2, 0);
    float mu   = s * (1.f / 192.f);
    float var  = s2 * (1.f / 192.f) - mu * mu;
    float rstd = rsqrtf(var + 1e-5f);

    bf16* orow = hn + (size_t)tok * D_MODEL;
#pragma unroll
    for (int i = 0; i < 3; ++i) {
        int d = tid + 64 * i;
        orow[d] = __float2bfloat16((v[i] - mu) * rstd * w[d] + b[d]);
    }
}

// ---------------------------------------------------------------------------
// bf16 MFMA GEMM: C[M,N] = A[M,K] * W[N,K]^T, fp32 accumulate/output.
// 128x128 block tile, BK=64, 4 waves (2x2), wave tile 64x64 = 4x4 MFMA
// (16x16x32). M % 128 == 0, K % 64 == 0; N may be ragged (clamped/masked).
// ---------------------------------------------------------------------------
__global__ __launch_bounds__(256) void gemm_mfma_k(
    const bf16* __restrict__ A, const bf16* __restrict__ W,
    float* __restrict__ C, int M, int N, int K)
{
    __shared__ __align__(16) bf16 As[128][64];   // 16 KB
    __shared__ __align__(16) bf16 Bs[128][64];   // 16 KB
    const int tid  = threadIdx.x;
    const int wave = tid >> 6;
    const int lane = tid & 63;
    const int m0 = blockIdx.x * 128, n0 = blockIdx.y * 128;
    const int wm = (wave >> 1) * 64;
    const int wn = (wave & 1) * 64;
    const int lrow = tid >> 3;     // 0..31
    const int lch  = tid & 7;      // 16B chunk within a 128B row

    f32x4 acc[4][4] = {};

    for (int k0 = 0; k0 < K; k0 += 64) {
#pragma unroll
        for (int j = 0; j < 4; ++j) {
            int r = lrow + 32 * j;
            *(float4*)(&As[r][lch * 8]) =
                *(const float4*)(A + (size_t)(m0 + r) * K + k0 + lch * 8);
            int rn = n0 + r; if (rn >= N) rn = N - 1;
            *(float4*)(&Bs[r][lch * 8]) =
                *(const float4*)(W + (size_t)rn * K + k0 + lch * 8);
        }
        __syncthreads();
#pragma unroll
        for (int kk = 0; kk < 64; kk += 32) {
            bf16x8 af[4], bfr[4];
#pragma unroll
            for (int i = 0; i < 4; ++i)
                af[i] = *(const bf16x8*)(&As[wm + i * 16 + (lane & 15)][kk + (lane >> 4) * 8]);
#pragma unroll
            for (int j = 0; j < 4; ++j)
                bfr[j] = *(const bf16x8*)(&Bs[wn + j * 16 + (lane & 15)][kk + (lane >> 4) * 8]);
#pragma unroll
            for (int i = 0; i < 4; ++i)
#pragma unroll
                for (int j = 0; j < 4; ++j)
                    acc[i][j] = __builtin_amdgcn_mfma_f32_16x16x32_bf16(
                        af[i], bfr[j], acc[i][j], 0, 0, 0);
        }
        __syncthreads();
    }

#pragma unroll
    for (int i = 0; i < 4; ++i) {
#pragma unroll
        for (int j = 0; j < 4; ++j) {
            int n = n0 + wn + j * 16 + (lane & 15);
            if (n < N) {
                int m = m0 + wm + i * 16 + (lane >> 4) * 4;
                float* cp = C + (size_t)m * N + n;
#pragma unroll
                for (int r = 0; r < 4; ++r) cp[(size_t)r * N] = acc[i][j][r];
            }
        }
    }
}

// ---------------------------------------------------------------------------
// Depthwise causal conv1d (k=4) + SiLU over x-half of xz; bf16 output (u).
// ---------------------------------------------------------------------------
__global__ __launch_bounds__(64) void conv_silu_k(
    const float* __restrict__ xz, const float* __restrict__ cw,
    const float* __restrict__ cb, bf16* __restrict__ xb)
{
    const int b = blockIdx.x;
    const int d = blockIdx.y * 64 + threadIdx.x;
    const float w0 = cw[d * 4 + 0], w1 = cw[d * 4 + 1],
                w2 = cw[d * 4 + 2], w3 = cw[d * 4 + 3];
    const float bias = cb[d];
    const float* src = xz + (size_t)b * L_SEQ * 768 + d;
    bf16*        dst = xb + (size_t)b * L_SEQ * D_INNER + d;

    float x0 = 0.f, x1 = 0.f, x2 = 0.f;
    for (int l = 0; l < L_SEQ; ++l) {
        float x3 = src[l * 768];
        float a  = w0 * x0 + w1 * x1 + w2 * x2 + w3 * x3 + bias;
        dst[l * D_INNER] = __float2bfloat16(a * sigmoidf_(a));
        x0 = x1; x1 = x2; x2 = x3;
    }
}

// ---------------------------------------------------------------------------
// Chunked parallel selective scan (fused dt_proj+softplus, D-skip, silu(z)).
// u (bf16) in, y (bf16) out; recurrence in fp32. y aliases u (reg-held).
// ---------------------------------------------------------------------------
__global__ __launch_bounds__(1024) void scan_chunked_k(
    const bf16* __restrict__ u, const float* __restrict__ xdbl,
    const float* __restrict__ xz,
    const float* __restrict__ dtw, const float* __restrict__ dtb,
    const float* __restrict__ A_log, const float* __restrict__ Dskip,
    bf16* __restrict__ y)
{
    __shared__ float hl[N_CHUNK * 64 * 17];
    __shared__ float dts[N_CHUNK * 64];

    const int b    = blockIdx.x;
    const int dg   = blockIdx.y;
    const int t    = threadIdx.x;
    const int lane = t & 63;
    const int wv   = t >> 6;
    const int d    = dg * 64 + lane;

    const float* xd = xdbl + (size_t)b * L_SEQ * 44;

    float A[D_STATE], wdt[DT_RANK];
    float dt[CH_LEN], uv[CH_LEN];
    float bdt = 0.f, Dv = 0.f;

    if (wv < N_CHUNK) {
#pragma unroll
        for (int n = 0; n < D_STATE; ++n) A[n] = -__expf(A_log[d * D_STATE + n]);
#pragma unroll
        for (int r = 0; r < DT_RANK; ++r) wdt[r] = dtw[d * DT_RANK + r];
        bdt = dtb[d];
        Dv  = Dskip[d];

        const int l0 = wv * CH_LEN;
        float h[D_STATE];
#pragma unroll
        for (int n = 0; n < D_STATE; ++n) h[n] = 0.f;
        float dtsum = 0.f;
#pragma unroll
        for (int s = 0; s < CH_LEN; ++s) {
            const int l = l0 + s;
            const float* row = xd + l * 44;
            float dtraw = bdt;
#pragma unroll
            for (int r = 0; r < DT_RANK; ++r) dtraw += row[r] * wdt[r];
            float dtv = (dtraw > 20.f) ? dtraw : log1pf(__expf(dtraw));
            dt[s] = dtv;
            dtsum += dtv;
            float uvv = __bfloat162float(u[((size_t)b * L_SEQ + l) * D_INNER + d]);
            uv[s] = uvv;
            float du = dtv * uvv;
#pragma unroll
            for (int n = 0; n < D_STATE; ++n)
                h[n] = __expf(dtv * A[n]) * h[n] + du * row[12 + n];
        }
#pragma unroll
        for (int n = 0; n < D_STATE; ++n)
            hl[(wv * 64 + lane) * 17 + n] = h[n];
        dts[wv * 64 + lane] = dtsum;
    }
    __syncthreads();

    {
        const int dB = lane;
        const int nB = wv;
        const float Ab = -__expf(A_log[(dg * 64 + dB) * D_STATE + nB]);
        float s = 0.f;
#pragma unroll
        for (int c = 0; c < N_CHUNK; ++c) {
            const int idx = (c * 64 + dB) * 17 + nB;
            float old = hl[idx];
            hl[idx] = s;
            s = __expf(Ab * dts[c * 64 + dB]) * s + old;
        }
    }
    __syncthreads();

    if (wv < N_CHUNK) {
        const int l0 = wv * CH_LEN;
        float h[D_STATE];
#pragma unroll
        for (int n = 0; n < D_STATE; ++n)
            h[n] = hl[(wv * 64 + lane) * 17 + n];
#pragma unroll
        for (int s = 0; s < CH_LEN; ++s) {
            const int l = l0 + s;
            const float* row = xd + l * 44;
            const float dtv = dt[s];
            const float du  = dtv * uv[s];
            float yv = 0.f;
#pragma unroll
            for (int n = 0; n < D_STATE; ++n) {
                h[n] = __expf(dtv * A[n]) * h[n] + du * row[12 + n];
                yv  += h[n] * row[28 + n];
            }
            yv += uv[s] * Dv;
            float zv = xz[((size_t)b * L_SEQ + l) * 768 + D_INNER + d];
            y[((size_t)b * L_SEQ + l) * D_INNER + d] =
                __float2bfloat16(yv * (zv * sigmoidf_(zv)));
        }
    }
}

// ---------------------------------------------------------------------------
// Final: residual+hidden at last token, LayerNorm -> pooled (64x192)
// ---------------------------------------------------------------------------
__global__ __launch_bounds__(64) void final_pool_k(
    const float* __restrict__ residual, const float* __restrict__ hidden,
    const float* __restrict__ w, const float* __restrict__ b,
    float* __restrict__ pooled)
{
    const int bi  = blockIdx.x;
    const int tid = threadIdx.x;
    const size_t off = ((size_t)bi * L_SEQ + (L_SEQ - 1)) * D_MODEL;

    float v[3];
    float s = 0.f, s2 = 0.f;
#pragma unroll
    for (int i = 0; i < 3; ++i) {
        int d = tid + 64 * i;
        float r = residual[off + d] + hidden[off + d];
        v[i] = r; s += r; s2 += r * r;
    }
#pragma unroll
    for (int offd = 32; offd > 0; offd >>= 1) {
        s  += __shfl_down(s, offd);
        s2 += __shfl_down(s2, offd);
    }
    s  = __shfl(s, 0);
    s2 = __shfl(s2, 0);
    float mu   = s * (1.f / 192.f);
    float var  = s2 * (1.f / 192.f) - mu * mu;
    float rstd = rsqrtf(var + 1e-5f);
#pragma unroll
    for (int i = 0; i < 3; ++i) {
        int d = tid + 64 * i;
        pooled[bi * D_MODEL + d] = (v[i] - mu) * rstd * w[d] + b[d];
    }
}

// ---------------------------------------------------------------------------
// Head: out[b,c] = pooled[b,:] . head_w[c,:] + head_b[c]
// ---------------------------------------------------------------------------
__global__ __launch_bounds__(256) void head_k(
    const float* __restrict__ pooled, const float* __restrict__ hw,
    const float* __restrict__ hb, float* __restrict__ out)
{
    __shared__ float p[D_MODEL];
    const int bi  = blockIdx.x;
    const int tid = threadIdx.x;
    if (tid < D_MODEL) p[tid] = pooled[bi * D_MODEL + tid];
    __syncthreads();
    int c = blockIdx.y * 256 + tid;
    if (c < N_CLS) {
        float acc = hb[c];
        const float* wrow = hw + (size_t)c * D_MODEL;
#pragma unroll 4
        for (int d = 0; d < D_MODEL; ++d) acc += p[d] * wrow[d];
        out[(size_t)bi * N_CLS + c] = acc;
    }
}

// ---------------------------------------------------------------------------
extern "C" void kernel_launch(void* const* d_in, const int* in_sizes, int n_in,
                              void* d_out, int out_size, void* d_ws, size_t ws_size,
                              hipStream_t stream)
{
    const float* x          = (const float*)d_in[0];
    const float* patch_w    = (const float*)d_in[1];
    const float* patch_b    = (const float*)d_in[2];
    const float* in_proj_w  = (const float*)d_in[3];
    const float* conv_w     = (const float*)d_in[4];
    const float* conv_b     = (const float*)d_in[5];
    const float* x_proj_w   = (const float*)d_in[6];
    const float* dt_proj_w  = (const float*)d_in[7];
    const float* dt_proj_b  = (const float*)d_in[8];
    const float* A_log      = (const float*)d_in[9];
    const float* D_skip     = (const float*)d_in[10];
    const float* out_proj_w = (const float*)d_in[11];
    const float* norm_w     = (const float*)d_in[12];
    const float* norm_b     = (const float*)d_in[13];
    const float* normf_w    = (const float*)d_in[14];
    const float* normf_b    = (const float*)d_in[15];
    const float* head_w     = (const float*)d_in[16];
    const float* head_b     = (const float*)d_in[17];
    float* out = (float*)d_out;

    // ---- workspace layout ----
    float* ws       = (float*)d_ws;
    float* residual = ws;                 // 2,408,448 f
    float* hidden   = ws + 2408448;       // 2,408,448 f
    float* xz       = ws + 4816896;       // 9,633,792 f  (B,L,768)
    float* xdbl     = ws + 14450688;      //   551,936 f  (B,L,44)
    float* pooled   = ws + 15002624;      //    12,288 f
    bf16* bfbase    = (bf16*)(ws + 15014912);
    bf16* hn_bf     = bfbase;             // 2,408,448
    bf16* xb_bf     = bfbase + 2408448;   // 4,816,896  (u then y)
    bf16* win_bf    = bfbase + 7225344;   // 3,538,944
    bf16* wx_bf     = bfbase + 10764288;  //   405,504
    bf16* wout_bf   = bfbase + 11169792;  // 1,769,472
    // total: 85.94 MB

    // weight conversions (every launch; deterministic)
    f2bf_k<<<(3538944 / 4 + 255) / 256, 256, 0, stream>>>(
        (const float4*)in_proj_w, (ushort4*)win_bf, 3538944 / 4);
    f2bf_k<<<(405504 / 4 + 255) / 256, 256, 0, stream>>>(
        (const float4*)x_proj_w, (ushort4*)wx_bf, 405504 / 4);
    f2bf_k<<<(1769472 / 4 + 255) / 256, 256, 0, stream>>>(
        (const float4*)out_proj_w, (ushort4*)wout_bf, 1769472 / 4);

    patch_embed_k<<<M_TOK / 8, 192, 0, stream>>>(x, patch_w, patch_b, hidden);

    for (int i = 0; i < DEPTH; ++i) {
        resid_ln_k<<<M_TOK, 64, 0, stream>>>(
            hidden, residual, hn_bf, norm_w + i * D_MODEL, norm_b + i * D_MODEL,
            (i == 0) ? 1 : 0);
        gemm_mfma_k<<<dim3(M_TOK / 128, 6), 256, 0, stream>>>(
            hn_bf, win_bf + (size_t)i * 768 * D_MODEL, xz, M_TOK, 768, D_MODEL);
        conv_silu_k<<<dim3(B_SZ, 6), 64, 0, stream>>>(
            xz, conv_w + (size_t)i * D_INNER * 4, conv_b + i * D_INNER, xb_bf);
        gemm_mfma_k<<<dim3(M_TOK / 128, 1), 256, 0, stream>>>(
            xb_bf, wx_bf + (size_t)i * 44 * D_INNER, xdbl, M_TOK, 44, D_INNER);
        scan_chunked_k<<<dim3(B_SZ, 6), 1024, 0, stream>>>(
            xb_bf, xdbl, xz,
            dt_proj_w + (size_t)i * D_INNER * DT_RANK, dt_proj_b + i * D_INNER,
            A_log + (size_t)i * D_INNER * D_STATE, D_skip + i * D_INNER, xb_bf);
        gemm_mfma_k<<<dim3(M_TOK / 128, 2), 256, 0, stream>>>(
            xb_bf, wout_bf + (size_t)i * D_MODEL * D_INNER, hidden, M_TOK, D_MODEL, D_INNER);
    }

    final_pool_k<<<B_SZ, 64, 0, stream>>>(residual, hidden, normf_w, normf_b, pooled);
    head_k<<<dim3(B_SZ, 4), 256, 0, stream>>>(pooled, head_w, head_b, out);
}